// Round 2
// baseline (19463.513 us; speedup 1.0000x reference)
//
#include <hip/hip_runtime.h>
#include <math.h>

#define SEQT 8192
#define HID  256
#define NTG  27
#define NEGV -10000.0f
#define START_TAG 25
#define STOP_TAG  26
#define POLL_LIM  (1 << 21)

// Teams: blocks 0..7 = L0 (64 waves), 8..15 = L1 (64 waves), 16 = EM (8 waves),
// 17 = CRF (wave 0 CRF loop, all 8 waves backtrace). 18 blocks x 512 threads.
#define L1_BASE 8
#define EM_BLK  16
#define CRF_BLK 17
#define NBLKS   18

// ---------- cross-XCD coherent primitives (L3 is the coherence point) -------
__device__ __forceinline__ float agent_load(const float* p) {
  return __hip_atomic_load(const_cast<float*>(p), __ATOMIC_RELAXED, __HIP_MEMORY_SCOPE_AGENT);
}
__device__ __forceinline__ void agent_store(float* p, float v) {
  __hip_atomic_store(p, v, __ATOMIC_RELAXED, __HIP_MEMORY_SCOPE_AGENT);
}
__device__ __forceinline__ float sigm(float x) { return 1.0f / (1.0f + __expf(-x)); }
__device__ __forceinline__ float tanh_f(float x) {
  x = fminf(15.0f, fmaxf(-15.0f, x));
  float e = __expf(-2.0f * x);
  return (1.0f - e) / (1.0f + e);
}

// ======================= layer-0 LSTM: 64 barrier-free waves ================
// Wave owns 4 cells. lane = (g = lane>>4 gate, r = lane&15 col-chunk).
// h-cols per lane: {k*16 + r}, k=0..15. x-cols per lane: {m*16 + r}, m=0..6.
__device__ void l0_run(int wid, const int* sent, const float* emb,
                       const float* w_ih0, const float* w_hh0,
                       const float* b_ih0, const float* b_hh0,
                       float* h0hist) {
  const int lane = threadIdx.x & 63;
  const int g = lane >> 4, r = lane & 15;
  const int cb = wid * 4;

  float wh[4][16], wx[4][7];
#pragma unroll
  for (int j = 0; j < 4; ++j) {
    const int row = g * 256 + cb + j;
#pragma unroll
    for (int k = 0; k < 16; ++k) wh[j][k] = w_hh0[row * 256 + k * 16 + r];
#pragma unroll
    for (int m = 0; m < 7; ++m) {
      int c = m * 16 + r;
      wx[j][m] = (c < 100) ? w_ih0[row * 100 + c] : 0.0f;
    }
  }
  float bI = 0, bF = 0, bG = 0, bO = 0, cst = 0.0f;
  if (lane < 4) {
    int cell = cb + lane;
    bI = b_ih0[cell]       + b_hh0[cell];
    bF = b_ih0[256 + cell] + b_hh0[256 + cell];
    bG = b_ih0[512 + cell] + b_hh0[512 + cell];
    bO = b_ih0[768 + cell] + b_hh0[768 + cell];
  }

  for (int t = 0; t < SEQT; ++t) {
    // issue x loads first; their latency hides under the h-poll
    float xv[7];
    {
      const int s = sent[t];
      const float* xrow = emb + (size_t)s * 100;
#pragma unroll
      for (int m = 0; m < 7; ++m) {
        int c = m * 16 + r;
        xv[m] = (c < 100) ? xrow[c] : 0.0f;
      }
    }
    float hv[16];
    if (t > 0) {
      const float* hp = h0hist + (size_t)(t - 1) * HID + r;
      int ctr = 0, ok;
      do {
        ok = 1;
#pragma unroll
        for (int k = 0; k < 16; ++k) {
          hv[k] = agent_load(hp + k * 16);
          ok &= (fabsf(hv[k]) < 2.0f);
        }
      } while (!ok && ++ctr < POLL_LIM);
    } else {
#pragma unroll
      for (int k = 0; k < 16; ++k) hv[k] = 0.0f;
    }
    float acc[4] = {0.f, 0.f, 0.f, 0.f};
#pragma unroll
    for (int m = 0; m < 7; ++m)
#pragma unroll
      for (int j = 0; j < 4; ++j) acc[j] = fmaf(wx[j][m], xv[m], acc[j]);
#pragma unroll
    for (int k = 0; k < 16; ++k)
#pragma unroll
      for (int j = 0; j < 4; ++j) acc[j] = fmaf(wh[j][k], hv[k], acc[j]);
    // in-group (16-lane) butterfly reduce of the 4 cell-partials
#pragma unroll
    for (int d = 1; d < 16; d <<= 1)
#pragma unroll
      for (int j = 0; j < 4; ++j) acc[j] += __shfl_xor(acc[j], d);
    // lane (16g + j) exposes gate-g sum of cell j; designated lanes 0..3 gather
    float v = (r == 0) ? acc[0] : (r == 1) ? acc[1] : (r == 2) ? acc[2] : acc[3];
    float gI = __shfl(v, lane);
    float gF = __shfl(v, 16 + lane);
    float gG = __shfl(v, 32 + lane);
    float gO = __shfl(v, 48 + lane);
    if (lane < 4) {
      float gi = sigm(gI + bI), gf = sigm(gF + bF);
      float gg = tanh_f(gG + bG), go = sigm(gO + bO);
      cst = gf * cst + gi * gg;
      agent_store(h0hist + (size_t)t * HID + cb + lane, go * tanh_f(cst));
    }
  }
}

// ======================= layer-1 LSTM: 64 barrier-free waves ================
__device__ void l1_run(int wid, const float* w_ih1, const float* w_hh1,
                       const float* b_ih1, const float* b_hh1,
                       const float* h0hist, float* h1hist) {
  const int lane = threadIdx.x & 63;
  const int g = lane >> 4, r = lane & 15;
  const int cb = wid * 4;

  float wx[4][16], wh[4][16];
#pragma unroll
  for (int j = 0; j < 4; ++j) {
    const int row = g * 256 + cb + j;
#pragma unroll
    for (int k = 0; k < 16; ++k) {
      wx[j][k] = w_ih1[row * 256 + k * 16 + r];
      wh[j][k] = w_hh1[row * 256 + k * 16 + r];
    }
  }
  float bI = 0, bF = 0, bG = 0, bO = 0, cst = 0.0f;
  if (lane < 4) {
    int cell = cb + lane;
    bI = b_ih1[cell]       + b_hh1[cell];
    bF = b_ih1[256 + cell] + b_hh1[256 + cell];
    bG = b_ih1[512 + cell] + b_hh1[512 + cell];
    bO = b_ih1[768 + cell] + b_hh1[768 + cell];
  }

  for (int t = 0; t < SEQT; ++t) {
    // h0[t] is produced ahead of us -> usually valid on first check
    float x0[16];
    {
      const float* hp = h0hist + (size_t)t * HID + r;
      int ctr = 0, ok;
      do {
        ok = 1;
#pragma unroll
        for (int k = 0; k < 16; ++k) {
          x0[k] = agent_load(hp + k * 16);
          ok &= (fabsf(x0[k]) < 2.0f);
        }
      } while (!ok && ++ctr < POLL_LIM);
    }
    // issue round-1 of the h1[t-1] poll, then do the x-half FMAs while waiting
    const float* hp1 = h1hist + (size_t)(t - 1) * HID + r;
    float hv[16];
    if (t > 0) {
#pragma unroll
      for (int k = 0; k < 16; ++k) hv[k] = agent_load(hp1 + k * 16);
    } else {
#pragma unroll
      for (int k = 0; k < 16; ++k) hv[k] = 0.0f;
    }
    float acc[4] = {0.f, 0.f, 0.f, 0.f};
#pragma unroll
    for (int k = 0; k < 16; ++k)
#pragma unroll
      for (int j = 0; j < 4; ++j) acc[j] = fmaf(wx[j][k], x0[k], acc[j]);
    if (t > 0) {
      int ctr = 0;
      for (;;) {
        int ok = 1;
#pragma unroll
        for (int k = 0; k < 16; ++k) ok &= (fabsf(hv[k]) < 2.0f);
        if (ok || ++ctr >= POLL_LIM) break;
#pragma unroll
        for (int k = 0; k < 16; ++k) hv[k] = agent_load(hp1 + k * 16);
      }
    }
#pragma unroll
    for (int k = 0; k < 16; ++k)
#pragma unroll
      for (int j = 0; j < 4; ++j) acc[j] = fmaf(wh[j][k], hv[k], acc[j]);
#pragma unroll
    for (int d = 1; d < 16; d <<= 1)
#pragma unroll
      for (int j = 0; j < 4; ++j) acc[j] += __shfl_xor(acc[j], d);
    float v = (r == 0) ? acc[0] : (r == 1) ? acc[1] : (r == 2) ? acc[2] : acc[3];
    float gI = __shfl(v, lane);
    float gF = __shfl(v, 16 + lane);
    float gG = __shfl(v, 32 + lane);
    float gO = __shfl(v, 48 + lane);
    if (lane < 4) {
      float gi = sigm(gI + bI), gf = sigm(gF + bF);
      float gg = tanh_f(gG + bG), go = sigm(gO + bO);
      cst = gf * cst + gi * gg;
      agent_store(h1hist + (size_t)t * HID + cb + lane, go * tanh_f(cst));
    }
  }
}

// =================== emission team: 8 waves, t mod 8, off critical path =====
// lane = (tp = lane>>1 tag, h = lane&1 col-half of 128). scores stored +1000.
__device__ void em_run(int wv, const float* w_lin, const float* b_lin,
                       const float* h1hist, float* scores) {
  const int lane = threadIdx.x & 63;
  const int tp = lane >> 1, h = lane & 1;
  const int tq = (tp < NTG) ? tp : NTG - 1;
  const bool active = (tp < NTG);

  float wl[128];
#pragma unroll
  for (int c = 0; c < 128; ++c) wl[c] = w_lin[tq * 256 + h * 128 + c];
  const float bl = b_lin[tq] + 1000.0f;

  for (int t = wv; t < SEQT; t += 8) {
    const float* hp = h1hist + (size_t)t * HID + h * 128;
    float acc;
    int ctr = 0, ok;
    do {
      ok = 1; acc = 0.0f;
#pragma unroll
      for (int c = 0; c < 128; ++c) {
        float v = agent_load(hp + c);
        ok &= (fabsf(v) < 2.0f);
        acc = fmaf(wl[c], v, acc);
      }
    } while (!ok && ++ctr < POLL_LIM);
    acc += __shfl_xor(acc, 1);
    if (active && h == 0) agent_store(scores + t * 32 + tp, acc + bl);
  }
}

// ============== CRF: wave 0 runs viterbi; whole block backtraces ============
// lanes 0..26 = tags (f-range 0..13), lanes 32..58 mirror tags (f-range 13..26).
__device__ void crf_run(const int* amask, const float* trans,
                        const float* scores, unsigned char* bpb, float* out) {
  __shared__ int btag[129];
  __shared__ int maps[128][NTG];
  const int tid = threadIdx.x;

  if ((tid >> 6) == 0) {
    const int lane = tid & 63;
    const int tau = lane & 31, half = lane >> 5;
    const bool act = (tau < NTG);
    const int tq = act ? tau : NTG - 1;

    float tc[14];
#pragma unroll
    for (int k = 0; k < 14; ++k) {
      int f = half ? (13 + k) : k;
      tc[k] = trans[f * NTG + tq];
    }
    const float tstop = trans[tq * NTG + STOP_TAG];
    float vreg = (act && tau == START_TAG) ? 0.0f : NEGV;

    for (int t = 0; t < SEQT; ++t) {
      float e = 0.0f;
      if (act) {
        const float* sp = scores + t * 32 + tau;
        int ctr = 0;
        e = agent_load(sp);
        while (e >= 2000.0f && ++ctr < POLL_LIM) e = agent_load(sp);
        e -= 1000.0f;
      }
      const int m = amask[t];
      float best = -3.0e38f; int barg = 0;
#pragma unroll
      for (int k = 0; k < 14; ++k) {       // hi half re-covers f=13: harmless for max
        int f = half ? (13 + k) : k;
        float vf = __shfl(vreg, half ? (45 + k) : k);
        float c = vf + tc[k];
        if (c > best) { best = c; barg = f; }  // ascending f + strict > = first-max
      }
      float ob = __shfl_xor(best, 32);
      int   oa = __shfl_xor(barg, 32);
      bool take = half ? (ob >= best) : (ob > best);  // ties -> lower f (lo half)
      if (take) { best = ob; barg = oa; }
      float vn = best + e;
      vreg = m ? vn : vreg;
      int bpv = m ? barg : tau;
      if (act && half == 0) bpb[(t << 5) + tau] = (unsigned char)bpv;
    }
    // terminal argmax with np first-max tie-break
    float tv = (act && half == 0) ? (vreg + tstop) : -3.0e38f;
    int   ti = (act && half == 0) ? tau : 64;
#pragma unroll
    for (int off = 32; off >= 1; off >>= 1) {
      float ov = __shfl_xor(tv, off);
      int   oi = __shfl_xor(ti, off);
      if ((ov > tv) || (ov == tv && oi < ti)) { tv = ov; ti = oi; }
    }
    if (lane == 0) { out[0] = tv; btag[128] = ti; }
  }
  __syncthreads();

  // per-64-step tag maps: 128 chunks x 27 end tags, 7 interleaved chains/thread
  {
    int bs[7], es[7], tg[7], nk = 0;
#pragma unroll
    for (int k = 0; k < 7; ++k) {
      int task = tid + k * 512;
      if (task < 128 * NTG) { bs[k] = task / NTG; es[k] = task % NTG; tg[k] = es[k]; nk = k + 1; }
      else { bs[k] = 0; es[k] = 0; tg[k] = 0; }
    }
    for (int i = 63; i >= 0; --i) {
#pragma unroll
      for (int k = 0; k < 7; ++k)
        if (k < nk) tg[k] = bpb[((bs[k] * 64 + i) << 5) + tg[k]];
    }
#pragma unroll
    for (int k = 0; k < 7; ++k) if (k < nk) maps[bs[k]][es[k]] = tg[k];
  }
  __syncthreads();

  if (tid == 0) {
    int e = btag[128];
    for (int b = 127; b >= 0; --b) { btag[b] = e; e = maps[b][e]; }
  }
  __syncthreads();

  if (tid < 128) {
    int b = tid, tag = btag[b];
    for (int i = 63; i >= 0; --i) {
      out[1 + b * 64 + i] = (float)tag;
      tag = bpb[((b * 64 + i) << 5) + tag];
    }
  }
}

// ===========================================================================
__global__ __launch_bounds__(512, 1)
void lstm_crf_pipeline(const int* sent, const int* amask, const float* emb,
                       const float* w_ih0, const float* w_hh0,
                       const float* b_ih0, const float* b_hh0,
                       const float* w_ih1, const float* w_hh1,
                       const float* b_ih1, const float* b_hh1,
                       const float* w_lin, const float* b_lin, const float* trans,
                       float* h0hist, float* h1hist, float* scores,
                       unsigned char* bpb, float* out) {
  const int b = blockIdx.x;
  const int wv = threadIdx.x >> 6;
  if (b < L1_BASE) {
    l0_run(b * 8 + wv, sent, emb, w_ih0, w_hh0, b_ih0, b_hh0, h0hist);
  } else if (b < EM_BLK) {
    l1_run((b - L1_BASE) * 8 + wv, w_ih1, w_hh1, b_ih1, b_hh1, h0hist, h1hist);
  } else if (b == EM_BLK) {
    em_run(wv, w_lin, b_lin, h1hist, scores);
  } else {
    crf_run(amask, trans, scores, bpb, out);
  }
}

extern "C" void kernel_launch(void* const* d_in, const int* in_sizes, int n_in,
                              void* d_out, int out_size, void* d_ws, size_t ws_size,
                              hipStream_t stream) {
  const int*   sent  = (const int*)d_in[0];
  const int*   amask = (const int*)d_in[1];
  const float* emb   = (const float*)d_in[2];
  const float* w_ih0 = (const float*)d_in[3];
  const float* w_hh0 = (const float*)d_in[4];
  const float* b_ih0 = (const float*)d_in[5];
  const float* b_hh0 = (const float*)d_in[6];
  const float* w_ih1 = (const float*)d_in[7];
  const float* w_hh1 = (const float*)d_in[8];
  const float* b_ih1 = (const float*)d_in[9];
  const float* b_hh1 = (const float*)d_in[10];
  const float* w_lin = (const float*)d_in[11];
  const float* b_lin = (const float*)d_in[12];
  const float* trans = (const float*)d_in[13];

  float* h0hist = (float*)d_ws;                       // 8192*256 f32
  float* h1hist = h0hist + (size_t)SEQT * HID;        // 8192*256 f32
  float* scores = h1hist + (size_t)SEQT * HID;        // 8192*32  f32 (+1000 offset)
  unsigned char* bpb = (unsigned char*)(scores + (size_t)SEQT * 32);  // 8192*32 B
  float* out = (float*)d_out;

  // re-arm sentinel (0x7F7F7F7F = 3.39e38: fails |v|<2 and v<2000) every call
  (void)hipMemsetAsync(d_ws, 0x7F,
                       ((size_t)2 * SEQT * HID + (size_t)SEQT * 32) * sizeof(float),
                       stream);

  lstm_crf_pipeline<<<NBLKS, 512, 0, stream>>>(
      sent, amask, emb, w_ih0, w_hh0, b_ih0, b_hh0,
      w_ih1, w_hh1, b_ih1, b_hh1, w_lin, b_lin, trans,
      h0hist, h1hist, scores, bpb, out);
}